// Round 2
// baseline (459.294 us; speedup 1.0000x reference)
//
#include <hip/hip_runtime.h>
#include <cstdint>
#include <cstddef>

typedef __attribute__((ext_vector_type(8))) short bf16x8;
typedef __attribute__((ext_vector_type(4))) float f32x4;
typedef __attribute__((ext_vector_type(4))) int   i32x4;

#define C_CH   256
#define NBOX   512      // B*N
#define FCDIM  1024
#define K1     12544    // C*7*7
#define OUTC   93

__device__ __forceinline__ unsigned short f2bf(float f) {
    unsigned u = __float_as_uint(f);
    u += 0x7fffu + ((u >> 16) & 1u);      // RNE
    return (unsigned short)(u >> 16);
}

// ---------------- cast f32 -> bf16, 8 elems/thread ----------------
__global__ __launch_bounds__(256) void cast_bf16_kernel(
    const float* __restrict__ in, short* __restrict__ out, int n8)
{
    int i = blockIdx.x * 256 + threadIdx.x;
    if (i >= n8) return;
    const float4* p = (const float4*)(in + (size_t)i * 8);
    float4 a = p[0], b = p[1];
    union { unsigned short s[8]; i32x4 v; } u;
    u.s[0] = f2bf(a.x); u.s[1] = f2bf(a.y); u.s[2] = f2bf(a.z); u.s[3] = f2bf(a.w);
    u.s[4] = f2bf(b.x); u.s[5] = f2bf(b.y); u.s[6] = f2bf(b.z); u.s[7] = f2bf(b.w);
    *(i32x4*)(out + (size_t)i * 8) = u.v;
}

// ---------------- ROI align: one block per (box, output-row py) ----------------
__global__ __launch_bounds__(256) void roi_kernel(
    const float* __restrict__ f0, const float* __restrict__ f1,
    const float* __restrict__ f2, const float* __restrict__ f3,
    const float* __restrict__ bbox, const int* __restrict__ aid,
    short* __restrict__ pooled)
{
    int bn = blockIdx.x;            // b*256 + n
    int py = blockIdx.y;            // 0..6
    int b  = bn >> 8;
    int t  = threadIdx.x;
    float yb = bbox[bn*4+0], xb = bbox[bn*4+1], hb = bbox[bn*4+2], wb = bbox[bn*4+3];
    int level = aid[bn] / 3;        // 0..3
    const float* fsrc = (level == 0) ? f0 : (level == 1) ? f1 : (level == 2) ? f2 : f3;
    int H = 128 >> level;           // square feature maps
    float scale = 1.0f / (float)(4 << level);
    const float* fp = fsrc + (size_t)b * C_CH * H * H;

    __shared__ int   xs0[14], xs1[14];
    __shared__ float wxs[14];
    __shared__ int   yro[4];        // row offsets: y0a*H, y1a*H, y0b*H, y1b*H
    __shared__ float wyv[2];

    if (t < 14) {
        float g  = ((float)t + 0.5f) * 0.5f;
        float l0 = (xb - 0.5f*wb) * scale - 0.5f;
        float bw = wb * scale * (1.0f/7.0f);
        float v  = fminf(fmaxf(l0 + bw * g, 0.0f), (float)(H-1));
        int i0 = (int)v;
        xs0[t] = i0; xs1[t] = min(i0 + 1, H - 1); wxs[t] = v - (float)i0;
    } else if (t < 16) {
        int ry = t - 14;
        int sy = py * 2 + ry;
        float g  = ((float)sy + 0.5f) * 0.5f;
        float t0 = (yb - 0.5f*hb) * scale - 0.5f;
        float bh = hb * scale * (1.0f/7.0f);
        float v  = fminf(fmaxf(t0 + bh * g, 0.0f), (float)(H-1));
        int i0 = (int)v;
        yro[ry*2]   = i0 * H;
        yro[ry*2+1] = min(i0 + 1, H - 1) * H;
        wyv[ry] = v - (float)i0;
    }
    __syncthreads();

    int r00 = yro[0], r01 = yro[1], r10 = yro[2], r11 = yro[3];
    float wy0 = wyv[0], wy1 = wyv[1];
    int HH = H * H;
    size_t outbase = (size_t)bn * K1 + (size_t)py * 7;

    #pragma unroll
    for (int it = 0; it < 7; ++it) {
        int oi = t + it * 256;       // < 1792 = 256 channels * 7 px
        int c  = oi / 7;
        int px = oi - c * 7;
        const float* fc = fp + (size_t)c * HH;
        int   xa0 = xs0[2*px],   xb0 = xs1[2*px];
        int   xa1 = xs0[2*px+1], xb1 = xs1[2*px+1];
        float wx0 = wxs[2*px],   wx1 = wxs[2*px+1];

        float v00 = fc[r00+xa0], v01 = fc[r00+xb0], v10 = fc[r01+xa0], v11 = fc[r01+xb0];
        float acc = (v00*(1.0f-wx0)+v01*wx0)*(1.0f-wy0) + (v10*(1.0f-wx0)+v11*wx0)*wy0;
        v00 = fc[r00+xa1]; v01 = fc[r00+xb1]; v10 = fc[r01+xa1]; v11 = fc[r01+xb1];
        acc += (v00*(1.0f-wx1)+v01*wx1)*(1.0f-wy0) + (v10*(1.0f-wx1)+v11*wx1)*wy0;
        v00 = fc[r10+xa0]; v01 = fc[r10+xb0]; v10 = fc[r11+xa0]; v11 = fc[r11+xb0];
        acc += (v00*(1.0f-wx0)+v01*wx0)*(1.0f-wy1) + (v10*(1.0f-wx0)+v11*wx0)*wy1;
        v00 = fc[r10+xa1]; v01 = fc[r10+xb1]; v10 = fc[r11+xa1]; v11 = fc[r11+xb1];
        acc += (v00*(1.0f-wx1)+v01*wx1)*(1.0f-wy1) + (v10*(1.0f-wx1)+v11*wx1)*wy1;

        pooled[outbase + (size_t)c * 49 + px] = (short)f2bf(acc * 0.25f);
    }
}

// ---------------- bf16 MFMA GEMM, 128x128 tile, 4 waves, 4x4 acc, split-K ----------------
// A:[M=512][K] bf16, Bt:[N=1024][K] bf16 (K-contiguous), part:[z][512][1024] f32
__global__ __launch_bounds__(256) void gemm_mfma(
    const short* __restrict__ A, const short* __restrict__ Bt,
    float* __restrict__ part, int K, int KC)
{
    __shared__ short As[128 * 32];
    __shared__ short Bs[128 * 32];
    int t = threadIdx.x, lane = t & 63, w = t >> 6;
    int m0 = blockIdx.y * 128, n0 = blockIdx.x * 128;
    size_t k0 = (size_t)blockIdx.z * KC;

    // staging: thread t covers row t>>1, cols (t&1)*16 .. +15 (two b128 per matrix)
    int srow = t >> 1, scol = (t & 1) * 16;
    const short* pa = A  + (size_t)(m0 + srow) * K + scol + k0;
    const short* pb = Bt + (size_t)(n0 + srow) * K + scol + k0;
    short* wa = &As[srow * 32 + scol];
    short* wb = &Bs[srow * 32 + scol];

    // fragment read addresses: wave quadrant (wr,wc), 4 m-subtiles x 4 n-subtiles
    int wr = (w >> 1) * 64, wc = (w & 1) * 64;
    int fr = lane & 15, kg = lane >> 4;
    const short* raf = &As[(wr + fr) * 32 + kg * 8];
    const short* rbf = &Bs[(wc + fr) * 32 + kg * 8];

    int nsteps = KC >> 5;
    i32x4 rA0 = *(const i32x4*)pa, rA1 = *(const i32x4*)(pa + 8);
    i32x4 rB0 = *(const i32x4*)pb, rB1 = *(const i32x4*)(pb + 8);

    f32x4 acc[4][4] = {};
    for (int s = 0; s < nsteps; ++s) {
        *(i32x4*)wa = rA0; *(i32x4*)(wa + 8) = rA1;
        *(i32x4*)wb = rB0; *(i32x4*)(wb + 8) = rB1;
        __syncthreads();
        if (s + 1 < nsteps) {          // issue next-tile loads early; latency hides under MFMA
            const short* na = pa + (size_t)(s + 1) * 32;
            const short* nb = pb + (size_t)(s + 1) * 32;
            rA0 = *(const i32x4*)na; rA1 = *(const i32x4*)(na + 8);
            rB0 = *(const i32x4*)nb; rB1 = *(const i32x4*)(nb + 8);
        }
        bf16x8 af[4], bm[4];
        #pragma unroll
        for (int i = 0; i < 4; i++) af[i] = *(const bf16x8*)(raf + i * 16 * 32);
        #pragma unroll
        for (int j = 0; j < 4; j++) bm[j] = *(const bf16x8*)(rbf + j * 16 * 32);
        #pragma unroll
        for (int i = 0; i < 4; i++)
            #pragma unroll
            for (int j = 0; j < 4; j++)
                acc[i][j] = __builtin_amdgcn_mfma_f32_16x16x32_bf16(af[i], bm[j], acc[i][j], 0, 0, 0);
        __syncthreads();
    }

    float* base = part + (size_t)blockIdx.z * NBOX * FCDIM;
    #pragma unroll
    for (int i = 0; i < 4; i++)
        #pragma unroll
        for (int j = 0; j < 4; j++)
            #pragma unroll
            for (int r = 0; r < 4; r++) {
                int row = m0 + wr + i * 16 + kg * 4 + r;
                int col = n0 + wc + j * 16 + fr;
                base[(size_t)row * FCDIM + col] = acc[i][j][r];
            }
}

// ---------------- BatchNorm over rows (512) + ReLU; sums split-K partials ----------------
__global__ __launch_bounds__(256) void bn_kernel(
    const float* __restrict__ part, float* __restrict__ xsum,
    const float* __restrict__ g, const float* __restrict__ be,
    short* __restrict__ out_bf, float* __restrict__ out_f, int nz)
{
    int tc = threadIdx.x & 31;
    int tr = threadIdx.x >> 5;
    int c  = blockIdx.x * 32 + tc;
    const size_t P = (size_t)NBOX * FCDIM;

    float s = 0.0f, q = 0.0f;
    for (int r = tr; r < NBOX; r += 8) {
        size_t o = (size_t)r * FCDIM + c;
        float x = 0.0f;
        for (int zz = 0; zz < nz; zz++) x += part[o + zz * P];
        xsum[o] = x;
        s += x; q += x * x;
    }
    __shared__ float Ss[8][32], Sq[8][32], sca[32], shf[32];
    Ss[tr][tc] = s; Sq[tr][tc] = q;
    __syncthreads();
    if (tr == 0) {
        float S = 0.0f, Q = 0.0f;
        #pragma unroll
        for (int i = 0; i < 8; i++) { S += Ss[i][tc]; Q += Sq[i][tc]; }
        float mu  = S * (1.0f / NBOX);
        float var = Q * (1.0f / NBOX) - mu * mu;
        float a = g[c] * rsqrtf(var + 1e-5f);
        sca[tc] = a;
        shf[tc] = be[c] - mu * a;
    }
    __syncthreads();
    float a = sca[tc], bsh = shf[tc];
    for (int r = tr; r < NBOX; r += 8) {
        size_t o = (size_t)r * FCDIM + c;
        float x = fmaxf(xsum[o] * a + bsh, 0.0f);
        if (out_bf) out_bf[o] = (short)f2bf(x);
        else        out_f[o]  = x;
    }
}

// ---------------- pred GEMV + bbox decode + softmax/sigmoid ----------------
__global__ __launch_bounds__(128) void pred_kernel(
    const float* __restrict__ xin, const float* __restrict__ pw,
    const float* __restrict__ pb, const float* __restrict__ bbox,
    const int* __restrict__ aid, const float* __restrict__ zp,
    float* __restrict__ out)
{
    int bn = blockIdx.x;
    int t  = threadIdx.x;
    __shared__ float xs[FCDIM];
    __shared__ float pr[OUTC];
    for (int i = t; i < FCDIM; i += 128)
        xs[i] = xin[(size_t)bn * FCDIM + i];
    __syncthreads();

    float z = zp[bn];
    if (t < OUTC) {
        const float* wrow = pw + (size_t)t * FCDIM;
        float acc = 0.0f;
        for (int k = 0; k < FCDIM; k += 4) {
            float4 w4 = *(const float4*)(wrow + k);
            acc += xs[k] * w4.x + xs[k+1] * w4.y + xs[k+2] * w4.z + xs[k+3] * w4.w;
        }
        pr[t] = (acc + pb[t]) * z;
    }
    __syncthreads();

    if (t < OUTC) {
        float y = bbox[bn*4+0], x = bbox[bn*4+1], h = bbox[bn*4+2], w = bbox[bn*4+3];
        int lvl = aid[bn] / 3;
        float st = 4.0f * exp2f((float)lvl * z);
        float o;
        if (t < 24) {
            int k = t / 6, j = t - k * 6;
            const float* d = &pr[5 + k * 6];
            switch (j) {
                case 0:  o = y + d[0] * h;  break;
                case 1:  o = x + d[1] * w;  break;
                case 2:  o = d[4] * st;     break;
                case 3:  o = h * expf(d[2]); break;
                case 4:  o = w * expf(d[3]); break;
                default: o = expf(d[5]) * st; break;
            }
        } else if (t < 29) {
            float m = pr[0];
            #pragma unroll
            for (int i = 1; i < 5; i++) m = fmaxf(m, pr[i]);
            float den = 0.0f;
            #pragma unroll
            for (int i = 0; i < 5; i++) den += expf(pr[i] - m);
            o = expf(pr[t - 24] - m) / den;
        } else if (t < 61) {
            int i = t - 29, k = i >> 3;
            const float* qq = &pr[29 + k * 8];
            float m = qq[0];
            #pragma unroll
            for (int ii = 1; ii < 8; ii++) m = fmaxf(m, qq[ii]);
            float den = 0.0f;
            #pragma unroll
            for (int ii = 0; ii < 8; ii++) den += expf(qq[ii] - m);
            o = expf(pr[t] - m) / den;
        } else {
            o = 1.0f / (1.0f + expf(-pr[t])) * 0.6f - 0.3f;
        }
        out[(size_t)bn * OUTC + t] = o;
    }
}

extern "C" void kernel_launch(void* const* d_in, const int* in_sizes, int n_in,
                              void* d_out, int out_size, void* d_ws, size_t ws_size,
                              hipStream_t stream)
{
    const float* f0   = (const float*)d_in[0];
    const float* f1   = (const float*)d_in[1];
    const float* f2   = (const float*)d_in[2];
    const float* f3   = (const float*)d_in[3];
    const float* bbox = (const float*)d_in[4];
    const int*   aid  = (const int*)d_in[5];
    const float* zp   = (const float*)d_in[6];
    const float* fc1w = (const float*)d_in[7];
    const float* bn1g = (const float*)d_in[9];
    const float* bn1b = (const float*)d_in[10];
    const float* fc2w = (const float*)d_in[11];
    const float* bn2g = (const float*)d_in[13];
    const float* bn2b = (const float*)d_in[14];
    const float* pw   = (const float*)d_in[15];
    const float* pb   = (const float*)d_in[16];
    float* out = (float*)d_out;

    // workspace layout (bytes) — lifetime-overlapped, peak 53.2 MB:
    //   [0 .. 12.85M)   pooled (bf16) ................. live: roi -> gemm1
    //   [0 .. 2.10M)    xsum (f32) .................... live: bn1 / bn2 (after gemm1)
    //   [2.10 .. 3.15M) x1n (bf16) .................... live: bn1 -> gemm2
    //   [3.15 .. 5.24M) w2 (bf16) ..................... live: cast_w2 (after gemm1) -> gemm2
    //   [5.24 .. 7.34M) x2n (f32) ..................... live: bn2 -> pred
    //   [12.85 .. 38.5M) w1 (bf16) .................... live: cast_w1 -> gemm1
    //   [12.85 .. 29.6M) part2 (f32, z=8) ............. live: gemm2 -> bn2 (w1 dead)
    //   [38.5 .. 53.2M) part1 (f32, z=7) .............. live: gemm1 -> bn1
    char* ws = (char*)d_ws;
    short* pooled = (short*)(ws);
    float* xsum   = (float*)(ws);
    short* x1n    = (short*)(ws + 2097152);
    short* w2     = (short*)(ws + 3145728);
    float* x2n    = (float*)(ws + 5242880);
    short* w1     = (short*)(ws + 12845056);
    float* part2  = (float*)(ws + 12845056);
    float* part1  = (float*)(ws + 38535168);

    cast_bf16_kernel<<<(K1 * FCDIM / 8 + 255) / 256, 256, 0, stream>>>(fc1w, w1, K1 * FCDIM / 8);

    roi_kernel<<<dim3(NBOX, 7), 256, 0, stream>>>(f0, f1, f2, f3, bbox, aid, pooled);

    dim3 g1(FCDIM / 128, NBOX / 128, 7);   // 8 x 4 x 7, KC = 1792
    gemm_mfma<<<g1, 256, 0, stream>>>(pooled, w1, part1, K1, K1 / 7);

    cast_bf16_kernel<<<(FCDIM * FCDIM / 8 + 255) / 256, 256, 0, stream>>>(fc2w, w2, FCDIM * FCDIM / 8);

    bn_kernel<<<FCDIM / 32, 256, 0, stream>>>(part1, xsum, bn1g, bn1b, x1n, nullptr, 7);

    dim3 g2(FCDIM / 128, NBOX / 128, 8);   // 8 x 4 x 8, KC = 128
    gemm_mfma<<<g2, 256, 0, stream>>>(x1n, w2, part2, FCDIM, FCDIM / 8);

    bn_kernel<<<FCDIM / 32, 256, 0, stream>>>(part2, xsum, bn2g, bn2b, nullptr, x2n, 8);

    pred_kernel<<<NBOX, 128, 0, stream>>>(x2n, pw, pb, bbox, aid, zp, out);
}

// Round 3
// 209.147 us; speedup vs baseline: 2.1960x; 2.1960x over previous
//
#include <hip/hip_runtime.h>
#include <cstdint>
#include <cstddef>

typedef __attribute__((ext_vector_type(8))) short bf16x8;
typedef __attribute__((ext_vector_type(4))) float f32x4;
typedef __attribute__((ext_vector_type(4))) int   i32x4;

#define C_CH   256
#define NBOX   512      // B*N
#define FCDIM  1024
#define K1     12544    // C*7*7
#define OUTC   93

__device__ __forceinline__ unsigned short f2bf(float f) {
    unsigned u = __float_as_uint(f);
    u += 0x7fffu + ((u >> 16) & 1u);      // RNE
    return (unsigned short)(u >> 16);
}

// ---------------- cast f32 -> bf16, 8 elems/thread ----------------
__global__ __launch_bounds__(256) void cast_bf16_kernel(
    const float* __restrict__ in, short* __restrict__ out, int n8)
{
    int i = blockIdx.x * 256 + threadIdx.x;
    if (i >= n8) return;
    const float4* p = (const float4*)(in + (size_t)i * 8);
    float4 a = p[0], b = p[1];
    union { unsigned short s[8]; i32x4 v; } u;
    u.s[0] = f2bf(a.x); u.s[1] = f2bf(a.y); u.s[2] = f2bf(a.z); u.s[3] = f2bf(a.w);
    u.s[4] = f2bf(b.x); u.s[5] = f2bf(b.y); u.s[6] = f2bf(b.z); u.s[7] = f2bf(b.w);
    *(i32x4*)(out + (size_t)i * 8) = u.v;
}

// ---------------- ROI align: one block per (box, output-row py) ----------------
__global__ __launch_bounds__(256) void roi_kernel(
    const float* __restrict__ f0, const float* __restrict__ f1,
    const float* __restrict__ f2, const float* __restrict__ f3,
    const float* __restrict__ bbox, const int* __restrict__ aid,
    short* __restrict__ pooled)
{
    int bn = blockIdx.x;            // b*256 + n
    int py = blockIdx.y;            // 0..6
    int b  = bn >> 8;
    int t  = threadIdx.x;
    float yb = bbox[bn*4+0], xb = bbox[bn*4+1], hb = bbox[bn*4+2], wb = bbox[bn*4+3];
    int level = aid[bn] / 3;        // 0..3
    const float* fsrc = (level == 0) ? f0 : (level == 1) ? f1 : (level == 2) ? f2 : f3;
    int H = 128 >> level;           // square feature maps
    float scale = 1.0f / (float)(4 << level);
    const float* fp = fsrc + (size_t)b * C_CH * H * H;

    __shared__ int   xs0[14], xs1[14];
    __shared__ float wxs[14];
    __shared__ int   yro[4];        // row offsets: y0a*H, y1a*H, y0b*H, y1b*H
    __shared__ float wyv[2];

    if (t < 14) {
        float g  = ((float)t + 0.5f) * 0.5f;
        float l0 = (xb - 0.5f*wb) * scale - 0.5f;
        float bw = wb * scale * (1.0f/7.0f);
        float v  = fminf(fmaxf(l0 + bw * g, 0.0f), (float)(H-1));
        int i0 = (int)v;
        xs0[t] = i0; xs1[t] = min(i0 + 1, H - 1); wxs[t] = v - (float)i0;
    } else if (t < 16) {
        int ry = t - 14;
        int sy = py * 2 + ry;
        float g  = ((float)sy + 0.5f) * 0.5f;
        float t0 = (yb - 0.5f*hb) * scale - 0.5f;
        float bh = hb * scale * (1.0f/7.0f);
        float v  = fminf(fmaxf(t0 + bh * g, 0.0f), (float)(H-1));
        int i0 = (int)v;
        yro[ry*2]   = i0 * H;
        yro[ry*2+1] = min(i0 + 1, H - 1) * H;
        wyv[ry] = v - (float)i0;
    }
    __syncthreads();

    int r00 = yro[0], r01 = yro[1], r10 = yro[2], r11 = yro[3];
    float wy0 = wyv[0], wy1 = wyv[1];
    int HH = H * H;
    size_t outbase = (size_t)bn * K1 + (size_t)py * 7;

    #pragma unroll
    for (int it = 0; it < 7; ++it) {
        int oi = t + it * 256;       // < 1792 = 256 channels * 7 px
        int c  = oi / 7;
        int px = oi - c * 7;
        const float* fc = fp + (size_t)c * HH;
        int   xa0 = xs0[2*px],   xb0 = xs1[2*px];
        int   xa1 = xs0[2*px+1], xb1 = xs1[2*px+1];
        float wx0 = wxs[2*px],   wx1 = wxs[2*px+1];

        float v00 = fc[r00+xa0], v01 = fc[r00+xb0], v10 = fc[r01+xa0], v11 = fc[r01+xb0];
        float acc = (v00*(1.0f-wx0)+v01*wx0)*(1.0f-wy0) + (v10*(1.0f-wx0)+v11*wx0)*wy0;
        v00 = fc[r00+xa1]; v01 = fc[r00+xb1]; v10 = fc[r01+xa1]; v11 = fc[r01+xb1];
        acc += (v00*(1.0f-wx1)+v01*wx1)*(1.0f-wy0) + (v10*(1.0f-wx1)+v11*wx1)*wy0;
        v00 = fc[r10+xa0]; v01 = fc[r10+xb0]; v10 = fc[r11+xa0]; v11 = fc[r11+xb0];
        acc += (v00*(1.0f-wx0)+v01*wx0)*(1.0f-wy1) + (v10*(1.0f-wx0)+v11*wx0)*wy1;
        v00 = fc[r10+xa1]; v01 = fc[r10+xb1]; v10 = fc[r11+xa1]; v11 = fc[r11+xb1];
        acc += (v00*(1.0f-wx1)+v01*wx1)*(1.0f-wy1) + (v10*(1.0f-wx1)+v11*wx1)*wy1;

        pooled[outbase + (size_t)c * 49 + px] = (short)f2bf(acc * 0.25f);
    }
}

// ---------------- bf16 MFMA GEMM, 128x128 tile, 4 waves, 4x4 acc, split-K ----------------
// A:[M=512][K] bf16, Bt:[N=1024][K] bf16 (K-contiguous), part:[z][512][1024] f32
__global__ __launch_bounds__(256) void gemm_mfma(
    const short* __restrict__ A, const short* __restrict__ Bt,
    float* __restrict__ part, int K, int KC)
{
    __shared__ short As[128 * 32];
    __shared__ short Bs[128 * 32];
    int t = threadIdx.x, lane = t & 63, w = t >> 6;
    int m0 = blockIdx.y * 128, n0 = blockIdx.x * 128;
    size_t k0 = (size_t)blockIdx.z * KC;

    // staging: thread t covers row t>>1, cols (t&1)*16 .. +15 (two b128 per matrix)
    int srow = t >> 1, scol = (t & 1) * 16;
    const short* pa = A  + (size_t)(m0 + srow) * K + scol + k0;
    const short* pb = Bt + (size_t)(n0 + srow) * K + scol + k0;
    short* wa = &As[srow * 32 + scol];
    short* wb = &Bs[srow * 32 + scol];

    // fragment read addresses: wave quadrant (wr,wc), 4 m-subtiles x 4 n-subtiles
    int wr = (w >> 1) * 64, wc = (w & 1) * 64;
    int fr = lane & 15, kg = lane >> 4;
    const short* raf = &As[(wr + fr) * 32 + kg * 8];
    const short* rbf = &Bs[(wc + fr) * 32 + kg * 8];

    int nsteps = KC >> 5;
    i32x4 rA0 = *(const i32x4*)pa, rA1 = *(const i32x4*)(pa + 8);
    i32x4 rB0 = *(const i32x4*)pb, rB1 = *(const i32x4*)(pb + 8);

    f32x4 acc[4][4] = {};
    for (int s = 0; s < nsteps; ++s) {
        *(i32x4*)wa = rA0; *(i32x4*)(wa + 8) = rA1;
        *(i32x4*)wb = rB0; *(i32x4*)(wb + 8) = rB1;
        __syncthreads();
        if (s + 1 < nsteps) {          // issue next-tile loads early; latency hides under MFMA
            const short* na = pa + (size_t)(s + 1) * 32;
            const short* nb = pb + (size_t)(s + 1) * 32;
            rA0 = *(const i32x4*)na; rA1 = *(const i32x4*)(na + 8);
            rB0 = *(const i32x4*)nb; rB1 = *(const i32x4*)(nb + 8);
        }
        bf16x8 af[4], bm[4];
        #pragma unroll
        for (int i = 0; i < 4; i++) af[i] = *(const bf16x8*)(raf + i * 16 * 32);
        #pragma unroll
        for (int j = 0; j < 4; j++) bm[j] = *(const bf16x8*)(rbf + j * 16 * 32);
        #pragma unroll
        for (int i = 0; i < 4; i++)
            #pragma unroll
            for (int j = 0; j < 4; j++)
                acc[i][j] = __builtin_amdgcn_mfma_f32_16x16x32_bf16(af[i], bm[j], acc[i][j], 0, 0, 0);
        __syncthreads();
    }

    float* base = part + (size_t)blockIdx.z * NBOX * FCDIM;
    #pragma unroll
    for (int i = 0; i < 4; i++)
        #pragma unroll
        for (int j = 0; j < 4; j++)
            #pragma unroll
            for (int r = 0; r < 4; r++) {
                int row = m0 + wr + i * 16 + kg * 4 + r;
                int col = n0 + wc + j * 16 + fr;
                base[(size_t)row * FCDIM + col] = acc[i][j][r];
            }
}

// ---------------- BN stage 1: sum split-K partials, per-block column stats ----------------
// grid (16 colgroups, 16 rowgroups); block = 64 cols x 4 row-lanes, 8 rows/lane
template<int NZ>
__global__ __launch_bounds__(256) void bn_stats1(
    const float* __restrict__ part, float* __restrict__ xsum, float* __restrict__ pstat)
{
    int tc = threadIdx.x & 63;
    int tr = threadIdx.x >> 6;
    int c  = blockIdx.x * 64 + tc;
    int r0 = blockIdx.y * 32;
    const size_t P = (size_t)NBOX * FCDIM;

    float s = 0.0f, q = 0.0f;
    #pragma unroll
    for (int rr = 0; rr < 8; rr++) {
        size_t o = (size_t)(r0 + tr + rr * 4) * FCDIM + c;
        float x = 0.0f;
        #pragma unroll
        for (int z = 0; z < NZ; z++) x += part[o + (size_t)z * P];
        xsum[o] = x;
        s += x; q += x * x;
    }
    __shared__ float Ss[4][64], Sq[4][64];
    Ss[tr][tc] = s; Sq[tr][tc] = q;
    __syncthreads();
    if (tr == 0) {
        float S = Ss[0][tc] + Ss[1][tc] + Ss[2][tc] + Ss[3][tc];
        float Q = Sq[0][tc] + Sq[1][tc] + Sq[2][tc] + Sq[3][tc];
        pstat[blockIdx.y * FCDIM + c] = S;
        pstat[16 * FCDIM + blockIdx.y * FCDIM + c] = Q;
    }
}

// ---------------- BN stage 2: finalize per-column scale/shift ----------------
__global__ __launch_bounds__(256) void bn_stats2(
    const float* __restrict__ pstat, const float* __restrict__ g,
    const float* __restrict__ be, float* __restrict__ scsh)
{
    int c = blockIdx.x * 256 + threadIdx.x;   // grid 4
    float S = 0.0f, Q = 0.0f;
    #pragma unroll
    for (int i = 0; i < 16; i++) {
        S += pstat[i * FCDIM + c];
        Q += pstat[16 * FCDIM + i * FCDIM + c];
    }
    float mu  = S * (1.0f / NBOX);
    float var = Q * (1.0f / NBOX) - mu * mu;
    float a = g[c] * rsqrtf(var + 1e-5f);
    scsh[c]         = a;
    scsh[FCDIM + c] = be[c] - mu * a;
}

// ---------------- BN stage 3: normalize + ReLU + store ----------------
template<bool BF>
__global__ __launch_bounds__(256) void bn_apply(
    const float* __restrict__ xsum, const float* __restrict__ scsh,
    short* __restrict__ obf, float* __restrict__ of)
{
    size_t base = ((size_t)blockIdx.x * 256 + threadIdx.x) * 8;   // grid 256
    int c0 = (int)(base & (FCDIM - 1));
    float4 x0 = *(const float4*)(xsum + base);
    float4 x1 = *(const float4*)(xsum + base + 4);
    float4 a0 = *(const float4*)(scsh + c0);
    float4 a1 = *(const float4*)(scsh + c0 + 4);
    float4 b0 = *(const float4*)(scsh + FCDIM + c0);
    float4 b1 = *(const float4*)(scsh + FCDIM + c0 + 4);
    float r[8];
    r[0] = fmaxf(x0.x*a0.x + b0.x, 0.0f);
    r[1] = fmaxf(x0.y*a0.y + b0.y, 0.0f);
    r[2] = fmaxf(x0.z*a0.z + b0.z, 0.0f);
    r[3] = fmaxf(x0.w*a0.w + b0.w, 0.0f);
    r[4] = fmaxf(x1.x*a1.x + b1.x, 0.0f);
    r[5] = fmaxf(x1.y*a1.y + b1.y, 0.0f);
    r[6] = fmaxf(x1.z*a1.z + b1.z, 0.0f);
    r[7] = fmaxf(x1.w*a1.w + b1.w, 0.0f);
    if (BF) {
        union { unsigned short s[8]; i32x4 v; } u;
        #pragma unroll
        for (int i = 0; i < 8; i++) u.s[i] = f2bf(r[i]);
        *(i32x4*)(obf + base) = u.v;
    } else {
        *(float4*)(of + base)     = *(float4*)&r[0];
        *(float4*)(of + base + 4) = *(float4*)&r[4];
    }
}

// ---------------- pred GEMV + bbox decode + softmax/sigmoid ----------------
__global__ __launch_bounds__(128) void pred_kernel(
    const float* __restrict__ xin, const float* __restrict__ pw,
    const float* __restrict__ pb, const float* __restrict__ bbox,
    const int* __restrict__ aid, const float* __restrict__ zp,
    float* __restrict__ out)
{
    int bn = blockIdx.x;
    int t  = threadIdx.x;
    __shared__ float xs[FCDIM];
    __shared__ float pr[OUTC];
    for (int i = t; i < FCDIM; i += 128)
        xs[i] = xin[(size_t)bn * FCDIM + i];
    __syncthreads();

    float z = zp[bn];
    if (t < OUTC) {
        const float* wrow = pw + (size_t)t * FCDIM;
        float acc = 0.0f;
        for (int k = 0; k < FCDIM; k += 4) {
            float4 w4 = *(const float4*)(wrow + k);
            acc += xs[k] * w4.x + xs[k+1] * w4.y + xs[k+2] * w4.z + xs[k+3] * w4.w;
        }
        pr[t] = (acc + pb[t]) * z;
    }
    __syncthreads();

    if (t < OUTC) {
        float y = bbox[bn*4+0], x = bbox[bn*4+1], h = bbox[bn*4+2], w = bbox[bn*4+3];
        int lvl = aid[bn] / 3;
        float st = 4.0f * exp2f((float)lvl * z);
        float o;
        if (t < 24) {
            int k = t / 6, j = t - k * 6;
            const float* d = &pr[5 + k * 6];
            switch (j) {
                case 0:  o = y + d[0] * h;  break;
                case 1:  o = x + d[1] * w;  break;
                case 2:  o = d[4] * st;     break;
                case 3:  o = h * expf(d[2]); break;
                case 4:  o = w * expf(d[3]); break;
                default: o = expf(d[5]) * st; break;
            }
        } else if (t < 29) {
            float m = pr[0];
            #pragma unroll
            for (int i = 1; i < 5; i++) m = fmaxf(m, pr[i]);
            float den = 0.0f;
            #pragma unroll
            for (int i = 0; i < 5; i++) den += expf(pr[i] - m);
            o = expf(pr[t - 24] - m) / den;
        } else if (t < 61) {
            int i = t - 29, k = i >> 3;
            const float* qq = &pr[29 + k * 8];
            float m = qq[0];
            #pragma unroll
            for (int ii = 1; ii < 8; ii++) m = fmaxf(m, qq[ii]);
            float den = 0.0f;
            #pragma unroll
            for (int ii = 0; ii < 8; ii++) den += expf(qq[ii] - m);
            o = expf(pr[t] - m) / den;
        } else {
            o = 1.0f / (1.0f + expf(-pr[t])) * 0.6f - 0.3f;
        }
        out[(size_t)bn * OUTC + t] = o;
    }
}

extern "C" void kernel_launch(void* const* d_in, const int* in_sizes, int n_in,
                              void* d_out, int out_size, void* d_ws, size_t ws_size,
                              hipStream_t stream)
{
    const float* f0   = (const float*)d_in[0];
    const float* f1   = (const float*)d_in[1];
    const float* f2   = (const float*)d_in[2];
    const float* f3   = (const float*)d_in[3];
    const float* bbox = (const float*)d_in[4];
    const int*   aid  = (const int*)d_in[5];
    const float* zp   = (const float*)d_in[6];
    const float* fc1w = (const float*)d_in[7];
    const float* bn1g = (const float*)d_in[9];
    const float* bn1b = (const float*)d_in[10];
    const float* fc2w = (const float*)d_in[11];
    const float* bn2g = (const float*)d_in[13];
    const float* bn2b = (const float*)d_in[14];
    const float* pw   = (const float*)d_in[15];
    const float* pb   = (const float*)d_in[16];
    float* out = (float*)d_out;

    // workspace layout (bytes) — lifetime-overlapped, peak ~53.4 MB:
    //   [0 .. 12.85M)    pooled (bf16) ................ live: roi -> gemm1
    //   [0 .. 2.10M)     xsum (f32) ................... live: bn1 / bn2 (after gemm1)
    //   [2.10 .. 3.15M)  x1n (bf16) ................... live: bn1 -> gemm2
    //   [3.15 .. 5.24M)  w2 (bf16) .................... live: cast_w2 (after gemm1) -> gemm2
    //   [5.24 .. 7.34M)  x2n (f32) .................... live: bn2 -> pred
    //   [12.85 .. 38.5M) w1 (bf16) .................... live: cast_w1 -> gemm1
    //   [12.85 .. 29.6M) part2 (f32, z=8) ............. live: gemm2 -> bn2 (w1 dead)
    //   [38.5 .. 53.2M)  part1 (f32, z=7) ............. live: gemm1 -> bn1
    //   [53.22 .. 53.35M) pstat .. [53.35 .. 53.36M) scsh
    char* ws = (char*)d_ws;
    short* pooled = (short*)(ws);
    float* xsum   = (float*)(ws);
    short* x1n    = (short*)(ws + 2097152);
    short* w2     = (short*)(ws + 3145728);
    float* x2n    = (float*)(ws + 5242880);
    short* w1     = (short*)(ws + 12845056);
    float* part2  = (float*)(ws + 12845056);
    float* part1  = (float*)(ws + 38535168);
    float* pstat  = (float*)(ws + 53215232);   // 2*16*1024*4 = 131072
    float* scsh   = (float*)(ws + 53346304);   // 2*1024*4 = 8192

    cast_bf16_kernel<<<(K1 * FCDIM / 8 + 255) / 256, 256, 0, stream>>>(fc1w, w1, K1 * FCDIM / 8);

    roi_kernel<<<dim3(NBOX, 7), 256, 0, stream>>>(f0, f1, f2, f3, bbox, aid, pooled);

    dim3 g1(FCDIM / 128, NBOX / 128, 7);   // 8 x 4 x 7, KC = 1792
    gemm_mfma<<<g1, 256, 0, stream>>>(pooled, w1, part1, K1, K1 / 7);

    cast_bf16_kernel<<<(FCDIM * FCDIM / 8 + 255) / 256, 256, 0, stream>>>(fc2w, w2, FCDIM * FCDIM / 8);

    bn_stats1<7><<<dim3(16, 16), 256, 0, stream>>>(part1, xsum, pstat);
    bn_stats2<<<4, 256, 0, stream>>>(pstat, bn1g, bn1b, scsh);
    bn_apply<true><<<256, 256, 0, stream>>>(xsum, scsh, x1n, nullptr);

    dim3 g2(FCDIM / 128, NBOX / 128, 8);   // 8 x 4 x 8, KC = 128
    gemm_mfma<<<g2, 256, 0, stream>>>(x1n, w2, part2, FCDIM, FCDIM / 8);

    bn_stats1<8><<<dim3(16, 16), 256, 0, stream>>>(part2, xsum, pstat);
    bn_stats2<<<4, 256, 0, stream>>>(pstat, bn2g, bn2b, scsh);
    bn_apply<false><<<256, 256, 0, stream>>>(xsum, scsh, nullptr, x2n);

    pred_kernel<<<NBOX, 128, 0, stream>>>(x2n, pw, pb, bbox, aid, zp, out);
}

// Round 4
// 201.900 us; speedup vs baseline: 2.2749x; 1.0359x over previous
//
#include <hip/hip_runtime.h>
#include <cstdint>
#include <cstddef>

typedef __attribute__((ext_vector_type(8))) short bf16x8;
typedef __attribute__((ext_vector_type(4))) float f32x4;
typedef __attribute__((ext_vector_type(4))) int   i32x4;

#define C_CH   256
#define NBOX   512      // B*N
#define FCDIM  1024
#define K1     12544    // C*7*7
#define OUTC   93

__device__ __forceinline__ unsigned short f2bf(float f) {
    unsigned u = __float_as_uint(f);
    u += 0x7fffu + ((u >> 16) & 1u);      // RNE
    return (unsigned short)(u >> 16);
}

// ---------------- cast f32 -> bf16, 8 elems/thread ----------------
__global__ __launch_bounds__(256) void cast_bf16_kernel(
    const float* __restrict__ in, short* __restrict__ out, int n8)
{
    int i = blockIdx.x * 256 + threadIdx.x;
    if (i >= n8) return;
    const float4* p = (const float4*)(in + (size_t)i * 8);
    float4 a = p[0], b = p[1];
    union { unsigned short s[8]; i32x4 v; } u;
    u.s[0] = f2bf(a.x); u.s[1] = f2bf(a.y); u.s[2] = f2bf(a.z); u.s[3] = f2bf(a.w);
    u.s[4] = f2bf(b.x); u.s[5] = f2bf(b.y); u.s[6] = f2bf(b.z); u.s[7] = f2bf(b.w);
    *(i32x4*)(out + (size_t)i * 8) = u.v;
}

// ---------------- ROI align: one block per (box, channel-group of 64) ----------------
// All 49 output px of a box stay in-block (tap-table + cache locality);
// channel split duplicates NOTHING (channels touch disjoint feature data).
__global__ __launch_bounds__(256) void roi_kernel(
    const float* __restrict__ f0, const float* __restrict__ f1,
    const float* __restrict__ f2, const float* __restrict__ f3,
    const float* __restrict__ bbox, const int* __restrict__ aid,
    short* __restrict__ pooled)
{
    int bn = blockIdx.x;            // b*256 + n
    int c0 = blockIdx.y * 64;       // channel group
    int b  = bn >> 8;
    int t  = threadIdx.x;
    float yb = bbox[bn*4+0], xb = bbox[bn*4+1], hb = bbox[bn*4+2], wb = bbox[bn*4+3];
    int level = aid[bn] / 3;        // 0..3
    const float* fsrc = (level == 0) ? f0 : (level == 1) ? f1 : (level == 2) ? f2 : f3;
    int H = 128 >> level;           // square feature maps
    float scale = 1.0f / (float)(4 << level);
    const float* fp = fsrc + (size_t)b * C_CH * H * H + (size_t)c0 * H * H;

    __shared__ int   xs0[14], xs1[14];
    __shared__ float wxs[14];
    __shared__ int   yr0[14], yr1[14];   // row offsets (pre-multiplied by H)
    __shared__ float wys[14];

    if (t < 14) {
        float g  = ((float)t + 0.5f) * 0.5f;
        float l0 = (xb - 0.5f*wb) * scale - 0.5f;
        float bw = wb * scale * (1.0f/7.0f);
        float v  = fminf(fmaxf(l0 + bw * g, 0.0f), (float)(H-1));
        int i0 = (int)v;
        xs0[t] = i0; xs1[t] = min(i0 + 1, H - 1); wxs[t] = v - (float)i0;
    } else if (t < 28) {
        int sy = t - 14;
        float g  = ((float)sy + 0.5f) * 0.5f;
        float t0 = (yb - 0.5f*hb) * scale - 0.5f;
        float bh = hb * scale * (1.0f/7.0f);
        float v  = fminf(fmaxf(t0 + bh * g, 0.0f), (float)(H-1));
        int i0 = (int)v;
        yr0[sy] = i0 * H;
        yr1[sy] = min(i0 + 1, H - 1) * H;
        wys[sy] = v - (float)i0;
    }
    __syncthreads();

    int HH = H * H;
    size_t outbase = (size_t)bn * K1 + (size_t)c0 * 49;

    #pragma unroll 2
    for (int it = 0; it < 13; ++it) {
        int oi = t + it * 256;       // < 3136 = 64 channels * 49 px
        if (oi >= 64 * 49) break;
        int c  = oi / 49;
        int s  = oi - c * 49;
        int py = s / 7, px = s - py * 7;
        const float* fc = fp + (size_t)c * HH;

        int   sy0 = 2*py, sy1 = 2*py + 1;
        int   sx0 = 2*px, sx1 = 2*px + 1;
        int   r00 = yr0[sy0], r01 = yr1[sy0], r10 = yr0[sy1], r11 = yr1[sy1];
        float wy0 = wys[sy0], wy1 = wys[sy1];
        int   xa0 = xs0[sx0], xb0 = xs1[sx0], xa1 = xs0[sx1], xb1 = xs1[sx1];
        float wx0 = wxs[sx0], wx1 = wxs[sx1];

        float v00 = fc[r00+xa0], v01 = fc[r00+xb0], v10 = fc[r01+xa0], v11 = fc[r01+xb0];
        float acc = (v00*(1.0f-wx0)+v01*wx0)*(1.0f-wy0) + (v10*(1.0f-wx0)+v11*wx0)*wy0;
        v00 = fc[r00+xa1]; v01 = fc[r00+xb1]; v10 = fc[r01+xa1]; v11 = fc[r01+xb1];
        acc += (v00*(1.0f-wx1)+v01*wx1)*(1.0f-wy0) + (v10*(1.0f-wx1)+v11*wx1)*wy0;
        v00 = fc[r10+xa0]; v01 = fc[r10+xb0]; v10 = fc[r11+xa0]; v11 = fc[r11+xb0];
        acc += (v00*(1.0f-wx0)+v01*wx0)*(1.0f-wy1) + (v10*(1.0f-wx0)+v11*wx0)*wy1;
        v00 = fc[r10+xa1]; v01 = fc[r10+xb1]; v10 = fc[r11+xa1]; v11 = fc[r11+xb1];
        acc += (v00*(1.0f-wx1)+v01*wx1)*(1.0f-wy1) + (v10*(1.0f-wx1)+v11*wx1)*wy1;

        pooled[outbase + oi] = (short)f2bf(acc * 0.25f);
    }
}

// ---------------- bf16 MFMA GEMM, 128x128 tile, 4 waves, 4x4 acc, split-K ----------------
// A:[M=512][K] bf16, Bt:[N=1024][K] bf16 (K-contiguous), part:[z][512][1024] f32
__global__ __launch_bounds__(256) void gemm_mfma(
    const short* __restrict__ A, const short* __restrict__ Bt,
    float* __restrict__ part, int K, int KC)
{
    __shared__ short As[128 * 32];
    __shared__ short Bs[128 * 32];
    int t = threadIdx.x, lane = t & 63, w = t >> 6;
    int m0 = blockIdx.y * 128, n0 = blockIdx.x * 128;
    size_t k0 = (size_t)blockIdx.z * KC;

    // staging: thread t covers row t>>1, cols (t&1)*16 .. +15 (two b128 per matrix)
    int srow = t >> 1, scol = (t & 1) * 16;
    const short* pa = A  + (size_t)(m0 + srow) * K + scol + k0;
    const short* pb = Bt + (size_t)(n0 + srow) * K + scol + k0;
    short* wa = &As[srow * 32 + scol];
    short* wb = &Bs[srow * 32 + scol];

    // fragment read addresses: wave quadrant (wr,wc), 4 m-subtiles x 4 n-subtiles
    int wr = (w >> 1) * 64, wc = (w & 1) * 64;
    int fr = lane & 15, kg = lane >> 4;
    const short* raf = &As[(wr + fr) * 32 + kg * 8];
    const short* rbf = &Bs[(wc + fr) * 32 + kg * 8];

    int nsteps = KC >> 5;
    i32x4 rA0 = *(const i32x4*)pa, rA1 = *(const i32x4*)(pa + 8);
    i32x4 rB0 = *(const i32x4*)pb, rB1 = *(const i32x4*)(pb + 8);

    f32x4 acc[4][4] = {};
    for (int s = 0; s < nsteps; ++s) {
        *(i32x4*)wa = rA0; *(i32x4*)(wa + 8) = rA1;
        *(i32x4*)wb = rB0; *(i32x4*)(wb + 8) = rB1;
        __syncthreads();
        if (s + 1 < nsteps) {          // issue next-tile loads early; latency hides under MFMA
            const short* na = pa + (size_t)(s + 1) * 32;
            const short* nb = pb + (size_t)(s + 1) * 32;
            rA0 = *(const i32x4*)na; rA1 = *(const i32x4*)(na + 8);
            rB0 = *(const i32x4*)nb; rB1 = *(const i32x4*)(nb + 8);
        }
        bf16x8 af[4], bm[4];
        #pragma unroll
        for (int i = 0; i < 4; i++) af[i] = *(const bf16x8*)(raf + i * 16 * 32);
        #pragma unroll
        for (int j = 0; j < 4; j++) bm[j] = *(const bf16x8*)(rbf + j * 16 * 32);
        #pragma unroll
        for (int i = 0; i < 4; i++)
            #pragma unroll
            for (int j = 0; j < 4; j++)
                acc[i][j] = __builtin_amdgcn_mfma_f32_16x16x32_bf16(af[i], bm[j], acc[i][j], 0, 0, 0);
        __syncthreads();
    }

    float* base = part + (size_t)blockIdx.z * NBOX * FCDIM;
    #pragma unroll
    for (int i = 0; i < 4; i++)
        #pragma unroll
        for (int j = 0; j < 4; j++)
            #pragma unroll
            for (int r = 0; r < 4; r++) {
                int row = m0 + wr + i * 16 + kg * 4 + r;
                int col = n0 + wc + j * 16 + fr;
                base[(size_t)row * FCDIM + col] = acc[i][j][r];
            }
}

// ---------------- BN stage 1: sum split-K partials, per-block column stats ----------------
// grid (16 colgroups, 16 rowgroups); block = 64 cols x 4 row-lanes, 8 rows/lane
template<int NZ>
__global__ __launch_bounds__(256) void bn_stats1(
    const float* __restrict__ part, float* __restrict__ xsum, float* __restrict__ pstat)
{
    int tc = threadIdx.x & 63;
    int tr = threadIdx.x >> 6;
    int c  = blockIdx.x * 64 + tc;
    int r0 = blockIdx.y * 32;
    const size_t P = (size_t)NBOX * FCDIM;

    float s = 0.0f, q = 0.0f;
    #pragma unroll
    for (int rr = 0; rr < 8; rr++) {
        size_t o = (size_t)(r0 + tr + rr * 4) * FCDIM + c;
        float x = 0.0f;
        #pragma unroll
        for (int z = 0; z < NZ; z++) x += part[o + (size_t)z * P];
        xsum[o] = x;
        s += x; q += x * x;
    }
    __shared__ float Ss[4][64], Sq[4][64];
    Ss[tr][tc] = s; Sq[tr][tc] = q;
    __syncthreads();
    if (tr == 0) {
        float S = Ss[0][tc] + Ss[1][tc] + Ss[2][tc] + Ss[3][tc];
        float Q = Sq[0][tc] + Sq[1][tc] + Sq[2][tc] + Sq[3][tc];
        pstat[blockIdx.y * FCDIM + c] = S;
        pstat[16 * FCDIM + blockIdx.y * FCDIM + c] = Q;
    }
}

// ---------------- BN stage 2: finalize per-column scale/shift ----------------
__global__ __launch_bounds__(256) void bn_stats2(
    const float* __restrict__ pstat, const float* __restrict__ g,
    const float* __restrict__ be, float* __restrict__ scsh)
{
    int c = blockIdx.x * 256 + threadIdx.x;   // grid 4
    float S = 0.0f, Q = 0.0f;
    #pragma unroll
    for (int i = 0; i < 16; i++) {
        S += pstat[i * FCDIM + c];
        Q += pstat[16 * FCDIM + i * FCDIM + c];
    }
    float mu  = S * (1.0f / NBOX);
    float var = Q * (1.0f / NBOX) - mu * mu;
    float a = g[c] * rsqrtf(var + 1e-5f);
    scsh[c]         = a;
    scsh[FCDIM + c] = be[c] - mu * a;
}

// ---------------- BN stage 3: normalize + ReLU + store ----------------
template<bool BF>
__global__ __launch_bounds__(256) void bn_apply(
    const float* __restrict__ xsum, const float* __restrict__ scsh,
    short* __restrict__ obf, float* __restrict__ of)
{
    size_t base = ((size_t)blockIdx.x * 256 + threadIdx.x) * 8;   // grid 256
    int c0 = (int)(base & (FCDIM - 1));
    float4 x0 = *(const float4*)(xsum + base);
    float4 x1 = *(const float4*)(xsum + base + 4);
    float4 a0 = *(const float4*)(scsh + c0);
    float4 a1 = *(const float4*)(scsh + c0 + 4);
    float4 b0 = *(const float4*)(scsh + FCDIM + c0);
    float4 b1 = *(const float4*)(scsh + FCDIM + c0 + 4);
    float r[8];
    r[0] = fmaxf(x0.x*a0.x + b0.x, 0.0f);
    r[1] = fmaxf(x0.y*a0.y + b0.y, 0.0f);
    r[2] = fmaxf(x0.z*a0.z + b0.z, 0.0f);
    r[3] = fmaxf(x0.w*a0.w + b0.w, 0.0f);
    r[4] = fmaxf(x1.x*a1.x + b1.x, 0.0f);
    r[5] = fmaxf(x1.y*a1.y + b1.y, 0.0f);
    r[6] = fmaxf(x1.z*a1.z + b1.z, 0.0f);
    r[7] = fmaxf(x1.w*a1.w + b1.w, 0.0f);
    if (BF) {
        union { unsigned short s[8]; i32x4 v; } u;
        #pragma unroll
        for (int i = 0; i < 8; i++) u.s[i] = f2bf(r[i]);
        *(i32x4*)(obf + base) = u.v;
    } else {
        *(float4*)(of + base)     = *(float4*)&r[0];
        *(float4*)(of + base + 4) = *(float4*)&r[4];
    }
}

// ---------------- pred GEMV + bbox decode + softmax/sigmoid ----------------
__global__ __launch_bounds__(128) void pred_kernel(
    const float* __restrict__ xin, const float* __restrict__ pw,
    const float* __restrict__ pb, const float* __restrict__ bbox,
    const int* __restrict__ aid, const float* __restrict__ zp,
    float* __restrict__ out)
{
    int bn = blockIdx.x;
    int t  = threadIdx.x;
    __shared__ float xs[FCDIM];
    __shared__ float pr[OUTC];
    for (int i = t; i < FCDIM; i += 128)
        xs[i] = xin[(size_t)bn * FCDIM + i];
    __syncthreads();

    float z = zp[bn];
    if (t < OUTC) {
        const float* wrow = pw + (size_t)t * FCDIM;
        float acc = 0.0f;
        for (int k = 0; k < FCDIM; k += 4) {
            float4 w4 = *(const float4*)(wrow + k);
            acc += xs[k] * w4.x + xs[k+1] * w4.y + xs[k+2] * w4.z + xs[k+3] * w4.w;
        }
        pr[t] = (acc + pb[t]) * z;
    }
    __syncthreads();

    if (t < OUTC) {
        float y = bbox[bn*4+0], x = bbox[bn*4+1], h = bbox[bn*4+2], w = bbox[bn*4+3];
        int lvl = aid[bn] / 3;
        float st = 4.0f * exp2f((float)lvl * z);
        float o;
        if (t < 24) {
            int k = t / 6, j = t - k * 6;
            const float* d = &pr[5 + k * 6];
            switch (j) {
                case 0:  o = y + d[0] * h;  break;
                case 1:  o = x + d[1] * w;  break;
                case 2:  o = d[4] * st;     break;
                case 3:  o = h * expf(d[2]); break;
                case 4:  o = w * expf(d[3]); break;
                default: o = expf(d[5]) * st; break;
            }
        } else if (t < 29) {
            float m = pr[0];
            #pragma unroll
            for (int i = 1; i < 5; i++) m = fmaxf(m, pr[i]);
            float den = 0.0f;
            #pragma unroll
            for (int i = 0; i < 5; i++) den += expf(pr[i] - m);
            o = expf(pr[t - 24] - m) / den;
        } else if (t < 61) {
            int i = t - 29, k = i >> 3;
            const float* qq = &pr[29 + k * 8];
            float m = qq[0];
            #pragma unroll
            for (int ii = 1; ii < 8; ii++) m = fmaxf(m, qq[ii]);
            float den = 0.0f;
            #pragma unroll
            for (int ii = 0; ii < 8; ii++) den += expf(qq[ii] - m);
            o = expf(pr[t] - m) / den;
        } else {
            o = 1.0f / (1.0f + expf(-pr[t])) * 0.6f - 0.3f;
        }
        out[(size_t)bn * OUTC + t] = o;
    }
}

extern "C" void kernel_launch(void* const* d_in, const int* in_sizes, int n_in,
                              void* d_out, int out_size, void* d_ws, size_t ws_size,
                              hipStream_t stream)
{
    const float* f0   = (const float*)d_in[0];
    const float* f1   = (const float*)d_in[1];
    const float* f2   = (const float*)d_in[2];
    const float* f3   = (const float*)d_in[3];
    const float* bbox = (const float*)d_in[4];
    const int*   aid  = (const int*)d_in[5];
    const float* zp   = (const float*)d_in[6];
    const float* fc1w = (const float*)d_in[7];
    const float* bn1g = (const float*)d_in[9];
    const float* bn1b = (const float*)d_in[10];
    const float* fc2w = (const float*)d_in[11];
    const float* bn2g = (const float*)d_in[13];
    const float* bn2b = (const float*)d_in[14];
    const float* pw   = (const float*)d_in[15];
    const float* pb   = (const float*)d_in[16];
    float* out = (float*)d_out;

    // workspace layout (bytes) — lifetime-overlapped, peak ~53.4 MB:
    //   [0 .. 12.85M)    pooled (bf16) ................ live: roi -> gemm1
    //   [0 .. 2.10M)     xsum (f32) ................... live: bn1 / bn2 (after gemm1)
    //   [2.10 .. 3.15M)  x1n (bf16) ................... live: bn1 -> gemm2
    //   [3.15 .. 5.24M)  w2 (bf16) .................... live: cast_w2 (after gemm1) -> gemm2
    //   [5.24 .. 7.34M)  x2n (f32) .................... live: bn2 -> pred
    //   [12.85 .. 38.5M) w1 (bf16) .................... live: cast_w1 -> gemm1
    //   [12.85 .. 29.6M) part2 (f32, z=8) ............. live: gemm2 -> bn2 (w1 dead)
    //   [38.5 .. 53.2M)  part1 (f32, z=7) ............. live: gemm1 -> bn1
    //   [53.22 .. 53.35M) pstat .. [53.35 .. 53.36M) scsh
    char* ws = (char*)d_ws;
    short* pooled = (short*)(ws);
    float* xsum   = (float*)(ws);
    short* x1n    = (short*)(ws + 2097152);
    short* w2     = (short*)(ws + 3145728);
    float* x2n    = (float*)(ws + 5242880);
    short* w1     = (short*)(ws + 12845056);
    float* part2  = (float*)(ws + 12845056);
    float* part1  = (float*)(ws + 38535168);
    float* pstat  = (float*)(ws + 53215232);   // 2*16*1024*4 = 131072
    float* scsh   = (float*)(ws + 53346304);   // 2*1024*4 = 8192

    cast_bf16_kernel<<<(K1 * FCDIM / 8 + 255) / 256, 256, 0, stream>>>(fc1w, w1, K1 * FCDIM / 8);

    roi_kernel<<<dim3(NBOX, 4), 256, 0, stream>>>(f0, f1, f2, f3, bbox, aid, pooled);

    dim3 g1(FCDIM / 128, NBOX / 128, 7);   // 8 x 4 x 7, KC = 1792
    gemm_mfma<<<g1, 256, 0, stream>>>(pooled, w1, part1, K1, K1 / 7);

    cast_bf16_kernel<<<(FCDIM * FCDIM / 8 + 255) / 256, 256, 0, stream>>>(fc2w, w2, FCDIM * FCDIM / 8);

    bn_stats1<7><<<dim3(16, 16), 256, 0, stream>>>(part1, xsum, pstat);
    bn_stats2<<<4, 256, 0, stream>>>(pstat, bn1g, bn1b, scsh);
    bn_apply<true><<<256, 256, 0, stream>>>(xsum, scsh, x1n, nullptr);

    dim3 g2(FCDIM / 128, NBOX / 128, 8);   // 8 x 4 x 8, KC = 128
    gemm_mfma<<<g2, 256, 0, stream>>>(x1n, w2, part2, FCDIM, FCDIM / 8);

    bn_stats1<8><<<dim3(16, 16), 256, 0, stream>>>(part2, xsum, pstat);
    bn_stats2<<<4, 256, 0, stream>>>(pstat, bn2g, bn2b, scsh);
    bn_apply<false><<<256, 256, 0, stream>>>(xsum, scsh, nullptr, x2n);

    pred_kernel<<<NBOX, 128, 0, stream>>>(x2n, pw, pb, bbox, aid, zp, out);
}

// Round 5
// 152.458 us; speedup vs baseline: 3.0126x; 1.3243x over previous
//
#include <hip/hip_runtime.h>
#include <cstdint>
#include <cstddef>

typedef __attribute__((ext_vector_type(8))) short bf16x8;
typedef __attribute__((ext_vector_type(4))) float f32x4;
typedef __attribute__((ext_vector_type(4))) int   i32x4;

#define C_CH   256
#define NBOX   512      // B*N
#define FCDIM  1024
#define K1     12544    // C*7*7
#define OUTC   93

__device__ __forceinline__ unsigned short f2bf(float f) {
    unsigned u = __float_as_uint(f);
    u += 0x7fffu + ((u >> 16) & 1u);      // RNE
    return (unsigned short)(u >> 16);
}
__device__ __forceinline__ float bf2f(short s) {
    return __uint_as_float((unsigned)(unsigned short)s << 16);
}

// ---------------- cast f32 -> bf16, 8 elems/thread ----------------
__global__ __launch_bounds__(256) void cast_bf16_kernel(
    const float* __restrict__ in, short* __restrict__ out, int n8)
{
    int i = blockIdx.x * 256 + threadIdx.x;
    if (i >= n8) return;
    const float4* p = (const float4*)(in + (size_t)i * 8);
    float4 a = p[0], b = p[1];
    union { unsigned short s[8]; i32x4 v; } u;
    u.s[0] = f2bf(a.x); u.s[1] = f2bf(a.y); u.s[2] = f2bf(a.z); u.s[3] = f2bf(a.w);
    u.s[4] = f2bf(b.x); u.s[5] = f2bf(b.y); u.s[6] = f2bf(b.z); u.s[7] = f2bf(b.w);
    *(i32x4*)(out + (size_t)i * 8) = u.v;
}

// ---------------- feature transpose: [B][C][HW] f32 -> [B][HW][C] bf16 ----------------
// tile: 128 pixels x 64 channels, LDS-staged; 512B/wave reads, 256B/wave writes
__global__ __launch_bounds__(256) void transpose_cl_kernel(
    const float* __restrict__ in, short* __restrict__ out, int HW)
{
    __shared__ short tile[128 * 66];
    int p0 = blockIdx.x * 128;
    int c0 = blockIdx.y * 64;
    int b  = blockIdx.z;
    const float* src = in + ((size_t)b * C_CH + c0) * HW + p0;
    int t = threadIdx.x;
    #pragma unroll
    for (int it = 0; it < 16; ++it) {
        int slot = it * 256 + t;           // over [64 ch][64 pixel-pairs]
        int cl = slot >> 6;
        int pp = slot & 63;
        float2 v = *(const float2*)(src + (size_t)cl * HW + pp * 2);
        tile[(pp * 2) * 66 + cl]     = (short)f2bf(v.x);
        tile[(pp * 2 + 1) * 66 + cl] = (short)f2bf(v.y);
    }
    __syncthreads();
    short* dst = out + ((size_t)b * HW + p0) * C_CH + c0;
    #pragma unroll
    for (int it = 0; it < 16; ++it) {
        int pl = it * 8 + (t >> 5);        // 0..127
        int c2 = (t & 31) * 2;
        *(unsigned*)(dst + (size_t)pl * C_CH + c2) = *(const unsigned*)&tile[pl * 66 + c2];
    }
}

// ---------------- ROI align v2: channel-last bf16 features, one block per box ----------------
// thread = (sub, channel); every tap load is 64 lanes x 2B consecutive (coalesced).
// Output staged in LDS (c*49+s layout), then written linearly.
__global__ __launch_bounds__(512) void roi_kernel(
    const short* __restrict__ g0, const short* __restrict__ g1,
    const short* __restrict__ g2, const short* __restrict__ g3,
    const float* __restrict__ bbox, const int* __restrict__ aid,
    short* __restrict__ pooled)
{
    int bn  = blockIdx.x;           // b*256 + n
    int b   = bn >> 8;
    int t   = threadIdx.x;
    int c   = t & 255;
    int sub = t >> 8;

    __shared__ int   xo0[14], xo1[14];   // x offsets premul by C_CH
    __shared__ float wxs[14];
    __shared__ int   yo0[14], yo1[14];   // y offsets premul by H*C_CH
    __shared__ float wys[14];
    __shared__ short otile[K1];          // [c*49 + s], 25088 B

    float yb = bbox[bn*4+0], xb = bbox[bn*4+1], hb = bbox[bn*4+2], wb = bbox[bn*4+3];
    int level = aid[bn] / 3;
    const short* gsrc = (level == 0) ? g0 : (level == 1) ? g1 : (level == 2) ? g2 : g3;
    int H = 128 >> level;
    float scale = 1.0f / (float)(4 << level);
    const short* gp = gsrc + (size_t)b * H * H * C_CH;

    if (t < 14) {
        float g  = ((float)t + 0.5f) * 0.5f;
        float l0 = (xb - 0.5f*wb) * scale - 0.5f;
        float bw = wb * scale * (1.0f/7.0f);
        float v  = fminf(fmaxf(l0 + bw * g, 0.0f), (float)(H-1));
        int i0 = (int)v;
        xo0[t] = i0 * C_CH;
        xo1[t] = min(i0 + 1, H - 1) * C_CH;
        wxs[t] = v - (float)i0;
    } else if (t < 28) {
        int sy = t - 14;
        float g  = ((float)sy + 0.5f) * 0.5f;
        float t0 = (yb - 0.5f*hb) * scale - 0.5f;
        float bh = hb * scale * (1.0f/7.0f);
        float v  = fminf(fmaxf(t0 + bh * g, 0.0f), (float)(H-1));
        int i0 = (int)v;
        yo0[sy] = i0 * H * C_CH;
        yo1[sy] = min(i0 + 1, H - 1) * H * C_CH;
        wys[sy] = v - (float)i0;
    }
    __syncthreads();

    #pragma unroll 2
    for (int s = sub; s < 49; s += 2) {
        int py = s / 7, px = s - py * 7;
        float acc = 0.0f;
        #pragma unroll
        for (int i = 0; i < 2; i++) {
            int sy = 2 * py + i;
            int ry0 = yo0[sy], ry1 = yo1[sy];
            float wy = wys[sy];
            #pragma unroll
            for (int j = 0; j < 2; j++) {
                int sx = 2 * px + j;
                int cx0 = xo0[sx] + c, cx1 = xo1[sx] + c;
                float wx = wxs[sx];
                float v00 = bf2f(gp[ry0 + cx0]);
                float v01 = bf2f(gp[ry0 + cx1]);
                float v10 = bf2f(gp[ry1 + cx0]);
                float v11 = bf2f(gp[ry1 + cx1]);
                float top = v00 * (1.0f - wx) + v01 * wx;
                float bot = v10 * (1.0f - wx) + v11 * wx;
                acc += top * (1.0f - wy) + bot * wy;
            }
        }
        otile[c * 49 + s] = (short)f2bf(acc * 0.25f);
    }
    __syncthreads();

    const i32x4* srcv = (const i32x4*)otile;
    i32x4* dstv = (i32x4*)(pooled + (size_t)bn * K1);
    for (int j = t; j < (K1 * 2) / 16; j += 512)   // 1568 chunks of 16B
        dstv[j] = srcv[j];
}

// ---------------- bf16 MFMA GEMM, 128x128 tile, 4 waves, 4x4 acc, split-K ----------------
// A:[M=512][K] bf16, Bt:[N=1024][K] bf16 (K-contiguous), part:[z][512][1024] f32
__global__ __launch_bounds__(256) void gemm_mfma(
    const short* __restrict__ A, const short* __restrict__ Bt,
    float* __restrict__ part, int K, int KC)
{
    __shared__ short As[128 * 32];
    __shared__ short Bs[128 * 32];
    int t = threadIdx.x, lane = t & 63, w = t >> 6;
    int m0 = blockIdx.y * 128, n0 = blockIdx.x * 128;
    size_t k0 = (size_t)blockIdx.z * KC;

    int srow = t >> 1, scol = (t & 1) * 16;
    const short* pa = A  + (size_t)(m0 + srow) * K + scol + k0;
    const short* pb = Bt + (size_t)(n0 + srow) * K + scol + k0;
    short* wa = &As[srow * 32 + scol];
    short* wb = &Bs[srow * 32 + scol];

    int wr = (w >> 1) * 64, wc = (w & 1) * 64;
    int fr = lane & 15, kg = lane >> 4;
    const short* raf = &As[(wr + fr) * 32 + kg * 8];
    const short* rbf = &Bs[(wc + fr) * 32 + kg * 8];

    int nsteps = KC >> 5;
    i32x4 rA0 = *(const i32x4*)pa, rA1 = *(const i32x4*)(pa + 8);
    i32x4 rB0 = *(const i32x4*)pb, rB1 = *(const i32x4*)(pb + 8);

    f32x4 acc[4][4] = {};
    for (int s = 0; s < nsteps; ++s) {
        *(i32x4*)wa = rA0; *(i32x4*)(wa + 8) = rA1;
        *(i32x4*)wb = rB0; *(i32x4*)(wb + 8) = rB1;
        __syncthreads();
        if (s + 1 < nsteps) {
            const short* na = pa + (size_t)(s + 1) * 32;
            const short* nb = pb + (size_t)(s + 1) * 32;
            rA0 = *(const i32x4*)na; rA1 = *(const i32x4*)(na + 8);
            rB0 = *(const i32x4*)nb; rB1 = *(const i32x4*)(nb + 8);
        }
        bf16x8 af[4], bm[4];
        #pragma unroll
        for (int i = 0; i < 4; i++) af[i] = *(const bf16x8*)(raf + i * 16 * 32);
        #pragma unroll
        for (int j = 0; j < 4; j++) bm[j] = *(const bf16x8*)(rbf + j * 16 * 32);
        #pragma unroll
        for (int i = 0; i < 4; i++)
            #pragma unroll
            for (int j = 0; j < 4; j++)
                acc[i][j] = __builtin_amdgcn_mfma_f32_16x16x32_bf16(af[i], bm[j], acc[i][j], 0, 0, 0);
        __syncthreads();
    }

    float* base = part + (size_t)blockIdx.z * NBOX * FCDIM;
    #pragma unroll
    for (int i = 0; i < 4; i++)
        #pragma unroll
        for (int j = 0; j < 4; j++)
            #pragma unroll
            for (int r = 0; r < 4; r++) {
                int row = m0 + wr + i * 16 + kg * 4 + r;
                int col = n0 + wc + j * 16 + fr;
                base[(size_t)row * FCDIM + col] = acc[i][j][r];
            }
}

// ---------------- BN stage 1: sum split-K partials, per-block column stats ----------------
template<int NZ>
__global__ __launch_bounds__(256) void bn_stats1(
    const float* __restrict__ part, float* __restrict__ xsum, float* __restrict__ pstat)
{
    int tc = threadIdx.x & 63;
    int tr = threadIdx.x >> 6;
    int c  = blockIdx.x * 64 + tc;
    int r0 = blockIdx.y * 32;
    const size_t P = (size_t)NBOX * FCDIM;

    float s = 0.0f, q = 0.0f;
    #pragma unroll
    for (int rr = 0; rr < 8; rr++) {
        size_t o = (size_t)(r0 + tr + rr * 4) * FCDIM + c;
        float x = 0.0f;
        #pragma unroll
        for (int z = 0; z < NZ; z++) x += part[o + (size_t)z * P];
        xsum[o] = x;
        s += x; q += x * x;
    }
    __shared__ float Ss[4][64], Sq[4][64];
    Ss[tr][tc] = s; Sq[tr][tc] = q;
    __syncthreads();
    if (tr == 0) {
        float S = Ss[0][tc] + Ss[1][tc] + Ss[2][tc] + Ss[3][tc];
        float Q = Sq[0][tc] + Sq[1][tc] + Sq[2][tc] + Sq[3][tc];
        pstat[blockIdx.y * FCDIM + c] = S;
        pstat[16 * FCDIM + blockIdx.y * FCDIM + c] = Q;
    }
}

// ---------------- BN stage 2: finalize per-column scale/shift ----------------
__global__ __launch_bounds__(256) void bn_stats2(
    const float* __restrict__ pstat, const float* __restrict__ g,
    const float* __restrict__ be, float* __restrict__ scsh)
{
    int c = blockIdx.x * 256 + threadIdx.x;   // grid 4
    float S = 0.0f, Q = 0.0f;
    #pragma unroll
    for (int i = 0; i < 16; i++) {
        S += pstat[i * FCDIM + c];
        Q += pstat[16 * FCDIM + i * FCDIM + c];
    }
    float mu  = S * (1.0f / NBOX);
    float var = Q * (1.0f / NBOX) - mu * mu;
    float a = g[c] * rsqrtf(var + 1e-5f);
    scsh[c]         = a;
    scsh[FCDIM + c] = be[c] - mu * a;
}

// ---------------- BN stage 3: normalize + ReLU + store ----------------
template<bool BF>
__global__ __launch_bounds__(256) void bn_apply(
    const float* __restrict__ xsum, const float* __restrict__ scsh,
    short* __restrict__ obf, float* __restrict__ of)
{
    size_t base = ((size_t)blockIdx.x * 256 + threadIdx.x) * 8;   // grid 256
    int c0 = (int)(base & (FCDIM - 1));
    float4 x0 = *(const float4*)(xsum + base);
    float4 x1 = *(const float4*)(xsum + base + 4);
    float4 a0 = *(const float4*)(scsh + c0);
    float4 a1 = *(const float4*)(scsh + c0 + 4);
    float4 b0 = *(const float4*)(scsh + FCDIM + c0);
    float4 b1 = *(const float4*)(scsh + FCDIM + c0 + 4);
    float r[8];
    r[0] = fmaxf(x0.x*a0.x + b0.x, 0.0f);
    r[1] = fmaxf(x0.y*a0.y + b0.y, 0.0f);
    r[2] = fmaxf(x0.z*a0.z + b0.z, 0.0f);
    r[3] = fmaxf(x0.w*a0.w + b0.w, 0.0f);
    r[4] = fmaxf(x1.x*a1.x + b1.x, 0.0f);
    r[5] = fmaxf(x1.y*a1.y + b1.y, 0.0f);
    r[6] = fmaxf(x1.z*a1.z + b1.z, 0.0f);
    r[7] = fmaxf(x1.w*a1.w + b1.w, 0.0f);
    if (BF) {
        union { unsigned short s[8]; i32x4 v; } u;
        #pragma unroll
        for (int i = 0; i < 8; i++) u.s[i] = f2bf(r[i]);
        *(i32x4*)(obf + base) = u.v;
    } else {
        *(float4*)(of + base)     = *(float4*)&r[0];
        *(float4*)(of + base + 4) = *(float4*)&r[4];
    }
}

// ---------------- pred GEMV + bbox decode + softmax/sigmoid ----------------
__global__ __launch_bounds__(128) void pred_kernel(
    const float* __restrict__ xin, const float* __restrict__ pw,
    const float* __restrict__ pb, const float* __restrict__ bbox,
    const int* __restrict__ aid, const float* __restrict__ zp,
    float* __restrict__ out)
{
    int bn = blockIdx.x;
    int t  = threadIdx.x;
    __shared__ float xs[FCDIM];
    __shared__ float pr[OUTC];
    for (int i = t; i < FCDIM; i += 128)
        xs[i] = xin[(size_t)bn * FCDIM + i];
    __syncthreads();

    float z = zp[bn];
    if (t < OUTC) {
        const float* wrow = pw + (size_t)t * FCDIM;
        float acc = 0.0f;
        for (int k = 0; k < FCDIM; k += 4) {
            float4 w4 = *(const float4*)(wrow + k);
            acc += xs[k] * w4.x + xs[k+1] * w4.y + xs[k+2] * w4.z + xs[k+3] * w4.w;
        }
        pr[t] = (acc + pb[t]) * z;
    }
    __syncthreads();

    if (t < OUTC) {
        float y = bbox[bn*4+0], x = bbox[bn*4+1], h = bbox[bn*4+2], w = bbox[bn*4+3];
        int lvl = aid[bn] / 3;
        float st = 4.0f * exp2f((float)lvl * z);
        float o;
        if (t < 24) {
            int k = t / 6, j = t - k * 6;
            const float* d = &pr[5 + k * 6];
            switch (j) {
                case 0:  o = y + d[0] * h;  break;
                case 1:  o = x + d[1] * w;  break;
                case 2:  o = d[4] * st;     break;
                case 3:  o = h * expf(d[2]); break;
                case 4:  o = w * expf(d[3]); break;
                default: o = expf(d[5]) * st; break;
            }
        } else if (t < 29) {
            float m = pr[0];
            #pragma unroll
            for (int i = 1; i < 5; i++) m = fmaxf(m, pr[i]);
            float den = 0.0f;
            #pragma unroll
            for (int i = 0; i < 5; i++) den += expf(pr[i] - m);
            o = expf(pr[t - 24] - m) / den;
        } else if (t < 61) {
            int i = t - 29, k = i >> 3;
            const float* qq = &pr[29 + k * 8];
            float m = qq[0];
            #pragma unroll
            for (int ii = 1; ii < 8; ii++) m = fmaxf(m, qq[ii]);
            float den = 0.0f;
            #pragma unroll
            for (int ii = 0; ii < 8; ii++) den += expf(qq[ii] - m);
            o = expf(pr[t] - m) / den;
        } else {
            o = 1.0f / (1.0f + expf(-pr[t])) * 0.6f - 0.3f;
        }
        out[(size_t)bn * OUTC + t] = o;
    }
}

extern "C" void kernel_launch(void* const* d_in, const int* in_sizes, int n_in,
                              void* d_out, int out_size, void* d_ws, size_t ws_size,
                              hipStream_t stream)
{
    const float* f0   = (const float*)d_in[0];
    const float* f1   = (const float*)d_in[1];
    const float* f2   = (const float*)d_in[2];
    const float* f3   = (const float*)d_in[3];
    const float* bbox = (const float*)d_in[4];
    const int*   aid  = (const int*)d_in[5];
    const float* zp   = (const float*)d_in[6];
    const float* fc1w = (const float*)d_in[7];
    const float* bn1g = (const float*)d_in[9];
    const float* bn1b = (const float*)d_in[10];
    const float* fc2w = (const float*)d_in[11];
    const float* bn2g = (const float*)d_in[13];
    const float* bn2b = (const float*)d_in[14];
    const float* pw   = (const float*)d_in[15];
    const float* pb   = (const float*)d_in[16];
    float* out = (float*)d_out;

    // workspace layout (bytes) — lifetime-overlapped, peak 53.36 MB (same as proven):
    //   [0 .. 12.85M)     pooled (bf16) ............... live: roi -> gemm1
    //   [0 .. 2.10M)      xsum (f32) .................. live: bn (after gemm1)
    //   [2.10 .. 3.15M)   x1n (bf16) .................. live: bn1 -> gemm2
    //   [3.15 .. 5.24M)   w2 (bf16) ................... live: cast_w2 (after gemm1) -> gemm2
    //   [5.24 .. 7.34M)   x2n (f32) ................... live: bn2 -> pred
    //   [12.85 .. 35.13M) gt0..gt3 (bf16, chan-last) .. live: transpose -> roi
    //   [12.85 .. 38.54M) w1 (bf16) ................... live: cast_w1 (AFTER roi) -> gemm1
    //   [12.85 .. 29.6M)  part2 (f32, z=8) ............ live: gemm2 -> bn2 (w1 dead)
    //   [38.54 .. 53.2M)  part1 (f32, z=7) ............ live: gemm1 -> bn1
    //   [53.22M) pstat  [53.35M) scsh
    char* ws = (char*)d_ws;
    short* pooled = (short*)(ws);
    float* xsum   = (float*)(ws);
    short* x1n    = (short*)(ws + 2097152);
    short* w2     = (short*)(ws + 3145728);
    float* x2n    = (float*)(ws + 5242880);
    short* gt0    = (short*)(ws + 12845056);   // 2*16384*256*2 = 16,777,216
    short* gt1    = (short*)(ws + 29622272);   // 2*4096*256*2  =  4,194,304
    short* gt2    = (short*)(ws + 33816576);   // 2*1024*256*2  =  1,048,576
    short* gt3    = (short*)(ws + 34865152);   // 2*256*256*2   =    262,144
    short* w1     = (short*)(ws + 12845056);
    float* part2  = (float*)(ws + 12845056);
    float* part1  = (float*)(ws + 38535168);
    float* pstat  = (float*)(ws + 53215232);
    float* scsh   = (float*)(ws + 53346304);

    transpose_cl_kernel<<<dim3(128, 4, 2), 256, 0, stream>>>(f0, gt0, 16384);
    transpose_cl_kernel<<<dim3( 32, 4, 2), 256, 0, stream>>>(f1, gt1,  4096);
    transpose_cl_kernel<<<dim3(  8, 4, 2), 256, 0, stream>>>(f2, gt2,  1024);
    transpose_cl_kernel<<<dim3(  2, 4, 2), 256, 0, stream>>>(f3, gt3,   256);

    roi_kernel<<<NBOX, 512, 0, stream>>>(gt0, gt1, gt2, gt3, bbox, aid, pooled);

    cast_bf16_kernel<<<(K1 * FCDIM / 8 + 255) / 256, 256, 0, stream>>>(fc1w, w1, K1 * FCDIM / 8);

    dim3 g1(FCDIM / 128, NBOX / 128, 7);   // 8 x 4 x 7, KC = 1792
    gemm_mfma<<<g1, 256, 0, stream>>>(pooled, w1, part1, K1, K1 / 7);

    cast_bf16_kernel<<<(FCDIM * FCDIM / 8 + 255) / 256, 256, 0, stream>>>(fc2w, w2, FCDIM * FCDIM / 8);

    bn_stats1<7><<<dim3(16, 16), 256, 0, stream>>>(part1, xsum, pstat);
    bn_stats2<<<4, 256, 0, stream>>>(pstat, bn1g, bn1b, scsh);
    bn_apply<true><<<256, 256, 0, stream>>>(xsum, scsh, x1n, nullptr);

    dim3 g2(FCDIM / 128, NBOX / 128, 8);   // 8 x 4 x 8, KC = 128
    gemm_mfma<<<g2, 256, 0, stream>>>(x1n, w2, part2, FCDIM, FCDIM / 8);

    bn_stats1<8><<<dim3(16, 16), 256, 0, stream>>>(part2, xsum, pstat);
    bn_stats2<<<4, 256, 0, stream>>>(pstat, bn2g, bn2b, scsh);
    bn_apply<false><<<256, 256, 0, stream>>>(xsum, scsh, nullptr, x2n);

    pred_kernel<<<NBOX, 128, 0, stream>>>(x2n, pw, pb, bbox, aid, zp, out);
}